// Round 7
// baseline (2512.485 us; speedup 1.0000x reference)
//
#include <hip/hip_runtime.h>
#include <hip/hip_fp16.h>
#include <cmath>

#define RN 512
#define RT 1024
#define RB 64
#define SMEM_BYTES 72704

typedef _Float16 half2v __attribute__((ext_vector_type(2)));

__device__ __forceinline__ float fast_tanh(float x) {
    float e = __expf(2.0f * x);
    return 1.0f - 2.0f / (e + 1.0f);
}
__device__ __forceinline__ unsigned pack2(float a, float b) {
    return (unsigned)__half_as_ushort(__float2half(a)) |
           ((unsigned)__half_as_ushort(__float2half(b)) << 16);
}
__device__ __forceinline__ float dot2(unsigned wa, unsigned tb, float acc) {
    half2v a = __builtin_bit_cast(half2v, wa);
    half2v b = __builtin_bit_cast(half2v, tb);
    return __builtin_amdgcn_fdot2(a, b, acc, false);
}
#define D2(acc, wv, tv) \
    acc = dot2((wv).x, (tv).x, acc); acc = dot2((wv).y, (tv).y, acc); \
    acc = dot2((wv).z, (tv).z, acc); acc = dot2((wv).w, (tv).w, acc);

// 256 blocks x 512 threads, cooperative, ~71 KB dynamic LDS (1 block/CU).
// 32 groups x 8 same-XCD blocks (XCC_ID + arrival rank). Group serves batches
// (g, g+32) in lockstep, sharing one W pass. Block = part p: rows [64p, 64p+64),
// W slice 64x512 f16-packed in LDS, uint4-XOR-swizzled by (row>>2)&7 (row%4 is
// constant per unrolled read -> this key gives <=2-way aliasing = free).
// Wave w <-> input band w (64 k): polls ONLY its producer's flag (relaxed agent,
// monotonic 2/step), loads the band from L2 (outH, fresh addresses -> no stale
// L1), stages wave-locally (lgkmcnt, no barrier), computes 4rows x 16k x 2batch
// partial dots, xor-reduces over the 4 chunk-lanes, writes stride-9 LDS
// partials. ONE __syncthreads joins; threads 0..127 (waves 0,1) then sum 8
// partials, update h, tanh, store outH, s_waitcnt vmcnt(0), and bump the
// group's part-flag. Self-ordering: wave w==part polls its own flag, so
// staging never races our own h-stores.
__global__ void __launch_bounds__(512, 1) rnn_step_kernel(
    const float* __restrict__ h0,
    const float* __restrict__ X,
    const float* __restrict__ W,
    const float* __restrict__ tanh0,
    float* __restrict__ outH,
    unsigned* __restrict__ flg,
    unsigned* __restrict__ xcdctr)
{
    extern __shared__ unsigned char smem[];
    uint4*    Wl4 = (uint4*)smem;                       // [64 rows][64 uint4]
    unsigned* stg = (unsigned*)(smem + 65536);          // [8 bands][2 batch][32]
    float*    pt  = (float*)(smem + 65536 + 2048);      // [(2*64) rows][9]
    int*      bc  = (int*)(smem + 65536 + 2048 + 4608);

    const int tid = threadIdx.x;
    if (tid == 0) {
        unsigned xcd;
        asm volatile("s_getreg_b32 %0, hwreg(HW_REG_XCC_ID)" : "=s"(xcd));
        xcd &= 7u;
        unsigned rank = __hip_atomic_fetch_add(&xcdctr[xcd], 1u,
                            __ATOMIC_RELAXED, __HIP_MEMORY_SCOPE_AGENT) & 31u;
        bc[0] = (int)(xcd * 4u + (rank >> 3));   // group 0..31
        bc[1] = (int)(rank & 7u);                // part  0..7
    }
    __syncthreads();
    const int group = bc[0], part = bc[1];
    const int bA = group, bB = group + 32;

    // ---- one-time: W slice -> LDS f16 pairs, uint4-swizzled ----
    for (int it = 0; it < 32; ++it) {
        int gidx = it * 512 + tid;          // pair index 0..16383
        int row  = gidx >> 8;               // 0..63
        int s    = gidx & 255;              // u32 pair-slot within row
        float2 wv = *reinterpret_cast<const float2*>(
            W + (size_t)(part * 64 + row) * RN + 2 * s);
        int u2 = (s >> 2) ^ ((row >> 2) & 7);
        reinterpret_cast<unsigned*>(Wl4)[row * 256 + u2 * 4 + (s & 3)] =
            pack2(wv.x, wv.y);
    }

    const int w    = tid >> 6;        // wave == band
    const int lane = tid & 63;
    const int kq   = (tid >> 4) & 3;  // chunk quarter within band
    const int rg   = tid & 15;        // row group (4 rows)
    const int swz  = rg & 7;

    // h-thread state (threads 0..127: wave0 = batch A, wave1 = batch B)
    const int hb     = tid >> 6;
    const int hrow   = tid & 63;
    const int hbatch = (hb == 0) ? bA : bB;
    const int grow   = part * 64 + hrow;
    float h = 0.f, xv = 0.f;
    if (tid < 128) {
        h  = h0[grow];
        xv = X[(size_t)hbatch * RT * RN + grow];
    }

    unsigned* myflg = flg + (group * 8 + part) * 16;
    unsigned* wflg  = flg + (group * 8 + w) * 16;

    __syncthreads();   // W staged

    #pragma unroll 1
    for (int t = 0; t < RT; ++t) {
        // 1. wait for band-w producer (skip t=0: flags start at 0)
        if (t > 0) {
            const unsigned tgt = 2u * (unsigned)t;
            while (__hip_atomic_load(wflg, __ATOMIC_RELAXED,
                                     __HIP_MEMORY_SCOPE_AGENT) < tgt)
                __builtin_amdgcn_s_sleep(1);
            asm volatile("" ::: "memory");
        }

        // 2. stage band w, both batches (lanes 0-31: A, 32-63: B)
        {
            const int hl   = lane & 31;
            const int bsel = lane >> 5;
            const float* src = (t == 0)
                ? (tanh0 + w * 64 + 2 * hl)
                : (outH + ((size_t)(bsel ? bB : bA) * RT + (t - 1)) * RN
                        + w * 64 + 2 * hl);
            float2 v = *reinterpret_cast<const float2*>(src);
            stg[(w * 2 + bsel) * 32 + hl] = pack2(v.x, v.y);
        }
        asm volatile("s_waitcnt lgkmcnt(0)" ::: "memory");  // wave-local RAW

        const uint4* sA = reinterpret_cast<const uint4*>(stg + (w * 2 + 0) * 32);
        const uint4* sB = reinterpret_cast<const uint4*>(stg + (w * 2 + 1) * 32);
        uint4 tA0 = sA[kq * 2 + 0], tA1 = sA[kq * 2 + 1];
        uint4 tB0 = sB[kq * 2 + 0], tB1 = sB[kq * 2 + 1];

        // 3. partial dots: 4 rows x 16 k x 2 batches
        float aA[4], aB[4];
        #pragma unroll
        for (int i = 0; i < 4; ++i) {
            const int row = 4 * rg + i;
            const uint4* wr = Wl4 + row * 64;
            const int ub = 8 * w + 2 * kq;
            uint4 w0 = wr[(ub + 0) ^ swz];
            uint4 w1 = wr[(ub + 1) ^ swz];
            float a = 0.f, b2 = 0.f;
            D2(a,  w0, tA0) D2(a,  w1, tA1)
            D2(b2, w0, tB0) D2(b2, w1, tB1)
            aA[i] = a; aB[i] = b2;
        }

        // 4. reduce over the 4 chunk-lanes (lane bits 4,5)
        #pragma unroll
        for (int i = 0; i < 4; ++i) {
            aA[i] += __shfl_xor(aA[i], 16); aA[i] += __shfl_xor(aA[i], 32);
            aB[i] += __shfl_xor(aB[i], 16); aB[i] += __shfl_xor(aB[i], 32);
        }
        if (lane < 16) {
            #pragma unroll
            for (int i = 0; i < 4; ++i) {
                pt[(4 * rg + i) * 9 + w]        = aA[i];
                pt[(64 + 4 * rg + i) * 9 + w]   = aB[i];
            }
        }

        __syncthreads();   // partials complete

        // 5. h-update, store, signal (waves 0,1 only; wave-uniform branch)
        if (tid < 128) {
            float s = 0.f;
            #pragma unroll
            for (int j = 0; j < 8; ++j)
                s += pt[(hb * 64 + hrow) * 9 + j];
            h = 0.9f * h + 0.1f * (s + xv);
            const float th = fast_tanh(h);
            outH[((size_t)hbatch * RT + t) * RN + grow] = th;
            asm volatile("s_waitcnt vmcnt(0)" ::: "memory");   // store in L2
            if ((tid & 63) == 0)
                __hip_atomic_fetch_add(myflg, 1u, __ATOMIC_RELAXED,
                                       __HIP_MEMORY_SCOPE_AGENT);
            if (t + 1 < RT)   // prefetch next x; hides under partner polls
                xv = X[((size_t)hbatch * RT + (t + 1)) * RN + grow];
        }
    }
}

// geometry epilogue: geo[b,t,:] = hidden[b,t,:] @ Gw^T + Gb ; one wave per (b,t)
__global__ void geom_kernel(const float* __restrict__ hid,
                            const float* __restrict__ Gw,
                            const float* __restrict__ Gb,
                            float* __restrict__ geo)
{
    const int wid  = (blockIdx.x * blockDim.x + threadIdx.x) >> 6;
    const int lane = threadIdx.x & 63;
    if (wid >= RB * RT) return;
    const float* rowp = hid + (size_t)wid * RN;
    float g0 = 0.f, g1 = 0.f;
    #pragma unroll
    for (int j = 0; j < 8; ++j) {
        float v = rowp[lane + 64 * j];
        g0 = fmaf(v, Gw[lane + 64 * j], g0);
        g1 = fmaf(v, Gw[RN + lane + 64 * j], g1);
    }
    #pragma unroll
    for (int m = 32; m >= 1; m >>= 1) {
        g0 += __shfl_xor(g0, m);
        g1 += __shfl_xor(g1, m);
    }
    if (lane == 0) {
        geo[(size_t)wid * 2]     = g0 + Gb[0];
        geo[(size_t)wid * 2 + 1] = g1 + Gb[1];
    }
}

// per-launch init: tanh(h0), zero flags + xcd rank counters (ws poisoned once,
// never re-poisoned -> re-init every call; deterministic)
__global__ void init_misc(const float* __restrict__ h0,
                          float* __restrict__ tanh0,
                          unsigned* __restrict__ flg,
                          unsigned* __restrict__ xcdctr)
{
    int i = blockIdx.x * blockDim.x + threadIdx.x;
    if (i < RN) tanh0[i] = tanhf(h0[i]);
    if (i < 32 * 8 * 16) flg[i] = 0u;
    if (i < 8) xcdctr[i] = 0u;
}

extern "C" void kernel_launch(void* const* d_in, const int* in_sizes, int n_in,
                              void* d_out, int out_size, void* d_ws, size_t ws_size,
                              hipStream_t stream)
{
    const float* h0 = (const float*)d_in[0];
    const float* X  = (const float*)d_in[1];
    const float* W  = (const float*)d_in[2];
    const float* Gw = (const float*)d_in[3];
    const float* Gb = (const float*)d_in[4];

    float* outH = (float*)d_out;
    float* geo  = outH + (size_t)RB * RT * RN;

    float* tanh0     = (float*)d_ws;                 // 512 f32
    unsigned* flg    = (unsigned*)d_ws + RN;         // 32*8*16 u32
    unsigned* xcdctr = flg + 32 * 8 * 16;            // 8 u32

    (void)hipFuncSetAttribute((const void*)rnn_step_kernel,
                              hipFuncAttributeMaxDynamicSharedMemorySize, SMEM_BYTES);

    init_misc<<<8, 512, 0, stream>>>(h0, tanh0, flg, xcdctr);

    void* kargs[] = { (void*)&h0, (void*)&X, (void*)&W, (void*)&tanh0,
                      (void*)&outH, (void*)&flg, (void*)&xcdctr };
    hipLaunchCooperativeKernel(rnn_step_kernel, dim3(256), dim3(512),
                               kargs, SMEM_BYTES, stream);

    geom_kernel<<<(RB * RT * 64 + 255) / 256, 256, 0, stream>>>(outH, Gw, Gb, geo);
}